// Round 1
// baseline (1987.923 us; speedup 1.0000x reference)
//
#include <hip/hip_runtime.h>

// Problem constants (fixed by the reference)
#define NN   50000
#define EE   800000
#define VIN  128
#define HIDN 128
#define UIN  64
#define MEMN 128
#define CATN 320
#define LN_EPS 1e-5f

// Fused-kernel tiling
#define NT   16            // nodes per block
#define LNS  321           // s_ln row stride (odd -> conflict-free scalar reads)
#define WTS  (32*321)      // weight tile buffer (floats): max of 32x321 and 64x132
#define SCS  132           // s_sc row stride
#define HSS  132           // s_h row stride

// ---------------------------------------------------------------------------
// K1: scatter-add  agg[dst] += edge_attr[e]   (atomics; agg pre-zeroed)
// ---------------------------------------------------------------------------
__global__ void scatter_add_kernel(const float* __restrict__ edge_attr,
                                   const int*   __restrict__ edge_dst,
                                   float*       __restrict__ agg)
{
    int gid = blockIdx.x * 256 + threadIdx.x;        // EE*32 = 25.6M threads
    if (gid >= EE * 32) return;
    int e  = gid >> 5;                               // edge id
    int c4 = gid & 31;                               // float4 slot within the 128-wide row
    float4 v = reinterpret_cast<const float4*>(edge_attr)[e * 32 + c4];
    float* p = agg + edge_dst[e] * HIDN + c4 * 4;
    atomicAdd(p + 0, v.x);
    atomicAdd(p + 1, v.y);
    atomicAdd(p + 2, v.z);
    atomicAdd(p + 3, v.w);
}

// ---------------------------------------------------------------------------
// K2: fused  concat -> LayerNorm -> external attention -> mix -> MLP -> out
//     One block = 16 nodes, 256 threads (4 waves). All f32 vector compute.
// ---------------------------------------------------------------------------
__global__ __launch_bounds__(256) void fused_node_kernel(
    const float* __restrict__ x,
    const float* __restrict__ agg,
    const float* __restrict__ u,
    const int*   __restrict__ batch,
    const float* __restrict__ Mk,
    const float* __restrict__ Mv,
    const float* __restrict__ gamma,
    const float* __restrict__ beta,
    const float* __restrict__ W1,
    const float* __restrict__ b1,
    const float* __restrict__ W2,
    const float* __restrict__ b2,
    float* __restrict__ out)
{
    __shared__ float s_ln[NT][LNS];   // normalized concat rows (later: mixed rows)
    __shared__ float s_wt[WTS];       // staged weight tiles (Mk/Mv/W1/W2)
    __shared__ float s_sc[NT][SCS];   // scores -> attention weights
    __shared__ float s_h[NT][HSS];    // MLP hidden

    const int tid   = threadIdx.x;
    const int node0 = blockIdx.x * NT;

    // ---- P0: gather concat + LayerNorm (one wave per node, 4 rounds) ----
    {
        const int lane = tid & 63;
        const int g    = tid >> 6;          // wave id 0..3
        for (int rep = 0; rep < 4; ++rep) {
            const int n  = g + rep * 4;     // node-in-block 0..15
            const int ng = node0 + n;
            const int bi = batch[ng];
            float v[5];
            #pragma unroll
            for (int j = 0; j < 5; ++j) {
                const int c = lane + 64 * j;        // uniform segment per j
                float val;
                if (c < 128)      val = x[ng * VIN + c];
                else if (c < 256) val = agg[ng * HIDN + (c - 128)];
                else              val = u[bi * UIN + (c - 256)];
                v[j] = val;
            }
            float s = 0.f, q = 0.f;
            #pragma unroll
            for (int j = 0; j < 5; ++j) { s += v[j]; q += v[j] * v[j]; }
            #pragma unroll
            for (int off = 32; off >= 1; off >>= 1) {
                s += __shfl_xor(s, off);
                q += __shfl_xor(q, off);
            }
            const float mu  = s * (1.0f / CATN);
            const float var = q * (1.0f / CATN) - mu * mu;
            const float rs  = rsqrtf(var + LN_EPS);
            #pragma unroll
            for (int j = 0; j < 5; ++j) {
                const int c = lane + 64 * j;
                s_ln[n][c] = (v[j] - mu) * rs * gamma[c] + beta[c];
            }
        }
    }
    __syncthreads();

    // ---- P1: scores[n][m] = ln[n] . Mk[m]   (K=320), m in 4 tiles of 32 ----
    {
        const int npair = tid & 7;          // 8 node-pairs
        const int mg    = tid >> 3;         // 0..31 local m
        const int n0 = npair * 2, n1 = n0 + 1;
        for (int mt = 0; mt < 4; ++mt) {
            for (int i = tid; i < 32 * CATN; i += 256) {
                const int r = i / CATN;
                const int c = i - r * CATN;
                s_wt[r * LNS + c] = Mk[(mt * 32 + r) * CATN + c];
            }
            __syncthreads();
            float acc0 = 0.f, acc1 = 0.f;
            const float* wrow = &s_wt[mg * LNS];
            #pragma unroll 4
            for (int c = 0; c < CATN; ++c) {
                const float w = wrow[c];
                acc0 += s_ln[n0][c] * w;
                acc1 += s_ln[n1][c] * w;
            }
            s_sc[n0][mt * 32 + mg] = acc0;
            s_sc[n1][mt * 32 + mg] = acc1;
            __syncthreads();
        }
    }

    // ---- P2: softmax over m (16 threads per node row) ----
    {
        const int r = tid >> 4;             // node 0..15
        const int j = tid & 15;
        float vals[8];
        float mx = -1e30f;
        #pragma unroll
        for (int k = 0; k < 8; ++k) {
            vals[k] = s_sc[r][j + 16 * k];
            mx = fmaxf(mx, vals[k]);
        }
        #pragma unroll
        for (int off = 8; off >= 1; off >>= 1) mx = fmaxf(mx, __shfl_xor(mx, off));
        float sum = 0.f;
        #pragma unroll
        for (int k = 0; k < 8; ++k) { vals[k] = __expf(vals[k] - mx); sum += vals[k]; }
        #pragma unroll
        for (int off = 8; off >= 1; off >>= 1) sum += __shfl_xor(sum, off);
        const float inv = 1.0f / sum;
        #pragma unroll
        for (int k = 0; k < 8; ++k) s_sc[r][j + 16 * k] = vals[k] * inv;
    }
    __syncthreads();

    // ---- P3: attn_out[n][c] = sum_m attn[n][m] * Mv[m][c]; mix into s_ln ----
    {
        const int n = tid >> 4;             // node 0..15
        const int j = tid & 15;             // c = j + 16k, k=0..19
        float acc[20];
        #pragma unroll
        for (int k = 0; k < 20; ++k) acc[k] = 0.f;
        for (int mt = 0; mt < 4; ++mt) {
            for (int i = tid; i < 32 * CATN; i += 256) {
                const int r = i / CATN;
                const int c = i - r * CATN;
                s_wt[r * LNS + c] = Mv[(mt * 32 + r) * CATN + c];
            }
            __syncthreads();
            #pragma unroll 4
            for (int m = 0; m < 32; ++m) {
                const float a = s_sc[n][mt * 32 + m];
                const float* wrow = &s_wt[m * LNS + j];
                #pragma unroll
                for (int k = 0; k < 20; ++k)
                    acc[k] += a * wrow[16 * k];
            }
            __syncthreads();
        }
        #pragma unroll
        for (int k = 0; k < 20; ++k) {
            const int c = j + 16 * k;
            s_ln[n][c] = 0.5f * acc[k] + 0.5f * s_ln[n][c];   // exclusive owner of (n,c)
        }
    }
    __syncthreads();

    // ---- P4: h = relu(mix @ W1 + b1)   (K=320 in 5 tiles of 64 rows) ----
    {
        const int npair = tid & 7;
        const int og    = tid >> 3;         // 0..31
        const int n0 = npair * 2, n1 = n0 + 1;
        const int o0 = og * 4;
        float acc[8];
        #pragma unroll
        for (int k = 0; k < 8; ++k) acc[k] = 0.f;
        for (int ct = 0; ct < 5; ++ct) {
            for (int i = tid; i < 64 * HIDN; i += 256) {
                const int r = i >> 7;
                const int o = i & 127;
                s_wt[r * HSS + o] = W1[(ct * 64 + r) * HIDN + o];
            }
            __syncthreads();
            #pragma unroll 4
            for (int cl = 0; cl < 64; ++cl) {
                const int c = ct * 64 + cl;
                const float a0 = s_ln[n0][c];
                const float a1 = s_ln[n1][c];
                const float4 w = *reinterpret_cast<const float4*>(&s_wt[cl * HSS + o0]);
                acc[0] += a0 * w.x; acc[1] += a0 * w.y; acc[2] += a0 * w.z; acc[3] += a0 * w.w;
                acc[4] += a1 * w.x; acc[5] += a1 * w.y; acc[6] += a1 * w.z; acc[7] += a1 * w.w;
            }
            __syncthreads();
        }
        float4 h0, h1;
        h0.x = fmaxf(acc[0] + b1[o0 + 0], 0.f);
        h0.y = fmaxf(acc[1] + b1[o0 + 1], 0.f);
        h0.z = fmaxf(acc[2] + b1[o0 + 2], 0.f);
        h0.w = fmaxf(acc[3] + b1[o0 + 3], 0.f);
        h1.x = fmaxf(acc[4] + b1[o0 + 0], 0.f);
        h1.y = fmaxf(acc[5] + b1[o0 + 1], 0.f);
        h1.z = fmaxf(acc[6] + b1[o0 + 2], 0.f);
        h1.w = fmaxf(acc[7] + b1[o0 + 3], 0.f);
        *reinterpret_cast<float4*>(&s_h[n0][o0]) = h0;
        *reinterpret_cast<float4*>(&s_h[n1][o0]) = h1;
    }
    __syncthreads();

    // ---- P5: y = h @ W2 + b2   (K=128 in 2 tiles of 64 rows) -> global ----
    {
        const int npair = tid & 7;
        const int og    = tid >> 3;
        const int n0 = npair * 2, n1 = n0 + 1;
        const int o0 = og * 4;
        float acc[8];
        #pragma unroll
        for (int k = 0; k < 8; ++k) acc[k] = 0.f;
        for (int ct = 0; ct < 2; ++ct) {
            for (int i = tid; i < 64 * HIDN; i += 256) {
                const int r = i >> 7;
                const int o = i & 127;
                s_wt[r * HSS + o] = W2[(ct * 64 + r) * HIDN + o];
            }
            __syncthreads();
            #pragma unroll 4
            for (int cl = 0; cl < 64; ++cl) {
                const int kk = ct * 64 + cl;
                const float a0 = s_h[n0][kk];
                const float a1 = s_h[n1][kk];
                const float4 w = *reinterpret_cast<const float4*>(&s_wt[cl * HSS + o0]);
                acc[0] += a0 * w.x; acc[1] += a0 * w.y; acc[2] += a0 * w.z; acc[3] += a0 * w.w;
                acc[4] += a1 * w.x; acc[5] += a1 * w.y; acc[6] += a1 * w.z; acc[7] += a1 * w.w;
            }
            __syncthreads();
        }
        float4 y0, y1;
        y0.x = acc[0] + b2[o0 + 0];
        y0.y = acc[1] + b2[o0 + 1];
        y0.z = acc[2] + b2[o0 + 2];
        y0.w = acc[3] + b2[o0 + 3];
        y1.x = acc[4] + b2[o0 + 0];
        y1.y = acc[5] + b2[o0 + 1];
        y1.z = acc[6] + b2[o0 + 2];
        y1.w = acc[7] + b2[o0 + 3];
        *reinterpret_cast<float4*>(&out[(node0 + n0) * HIDN + o0]) = y0;
        *reinterpret_cast<float4*>(&out[(node0 + n1) * HIDN + o0]) = y1;
    }
}

// ---------------------------------------------------------------------------
extern "C" void kernel_launch(void* const* d_in, const int* in_sizes, int n_in,
                              void* d_out, int out_size, void* d_ws, size_t ws_size,
                              hipStream_t stream)
{
    const float* x         = (const float*)d_in[0];
    const int*   edge_idx  = (const int*)  d_in[1];   // [2,E] int32
    const float* edge_attr = (const float*)d_in[2];
    const float* u         = (const float*)d_in[3];
    const int*   batch     = (const int*)  d_in[4];
    const float* Mk        = (const float*)d_in[5];
    const float* Mv        = (const float*)d_in[6];
    const float* gamma     = (const float*)d_in[7];
    const float* beta      = (const float*)d_in[8];
    const float* W1        = (const float*)d_in[9];
    const float* b1        = (const float*)d_in[10];
    const float* W2        = (const float*)d_in[11];
    const float* b2        = (const float*)d_in[12];
    float*       out       = (float*)d_out;

    float* agg = (float*)d_ws;                         // N*128 f32 = 25.6 MB

    hipMemsetAsync(agg, 0, (size_t)NN * HIDN * sizeof(float), stream);

    const int* edge_dst = edge_idx + EE;               // row 1 of edge_index
    const int sc_threads = EE * 32;
    scatter_add_kernel<<<(sc_threads + 255) / 256, 256, 0, stream>>>(edge_attr, edge_dst, agg);

    fused_node_kernel<<<NN / NT, 256, 0, stream>>>(x, agg, u, batch, Mk, Mv,
                                                   gamma, beta, W1, b1, W2, b2, out);
}

// Round 2
// 841.128 us; speedup vs baseline: 2.3634x; 2.3634x over previous
//
#include <hip/hip_runtime.h>

// Problem constants (fixed by the reference)
#define NN   50000
#define EE   800000
#define VIN  128
#define HIDN 128
#define UIN  64
#define MEMN 128
#define CATN 320
#define LN_EPS 1e-5f

// Fused-kernel tiling
#define NT   16            // nodes per block
#define LNS  321           // s_ln row stride (odd -> conflict-free scalar reads)
#define WTS  (32*321)      // weight tile buffer (floats): max of 32x321 and 64x132
#define SCS  132           // s_sc row stride
#define HSS  132           // s_h row stride

#define SCAN_NB 196        // ceil(50000/256)

// ---------------------------------------------------------------------------
// CSR build: histogram -> scan -> bucket fill, then gather-sum (no f32 atomics)
// ---------------------------------------------------------------------------
__global__ void hist_kernel(const int* __restrict__ edge_dst, int* __restrict__ count)
{
    int gid = blockIdx.x * 256 + threadIdx.x;
    if (gid < EE) atomicAdd(&count[edge_dst[gid]], 1);
}

__global__ void block_sum_kernel(const int* __restrict__ count, int* __restrict__ partials)
{
    __shared__ int s[256];
    const int tid = threadIdx.x;
    const int gid = blockIdx.x * 256 + tid;
    s[tid] = (gid < NN) ? count[gid] : 0;
    __syncthreads();
    for (int off = 128; off >= 1; off >>= 1) {
        if (tid < off) s[tid] += s[tid + off];
        __syncthreads();
    }
    if (tid == 0) partials[blockIdx.x] = s[0];
}

__global__ void scan_partials_kernel(int* __restrict__ partials)
{
    __shared__ int s[256];
    const int tid = threadIdx.x;
    const int v = (tid < SCAN_NB) ? partials[tid] : 0;
    s[tid] = v;
    __syncthreads();
    for (int off = 1; off < 256; off <<= 1) {
        int t = (tid >= off) ? s[tid - off] : 0;
        __syncthreads();
        s[tid] += t;
        __syncthreads();
    }
    if (tid < SCAN_NB) partials[tid] = s[tid] - v;   // exclusive
}

__global__ void make_offsets_kernel(const int* __restrict__ count,
                                    const int* __restrict__ partials,
                                    int* __restrict__ offsets)
{
    __shared__ int s[256];
    const int tid = threadIdx.x;
    const int gid = blockIdx.x * 256 + tid;
    const int v = (gid < NN) ? count[gid] : 0;
    s[tid] = v;
    __syncthreads();
    for (int off = 1; off < 256; off <<= 1) {
        int t = (tid >= off) ? s[tid - off] : 0;
        __syncthreads();
        s[tid] += t;
        __syncthreads();
    }
    if (gid < NN) offsets[gid] = partials[blockIdx.x] + s[tid] - v;  // exclusive
}

__global__ void fill_kernel(const int* __restrict__ edge_dst,
                            const int* __restrict__ offsets,
                            int* __restrict__ cursor,
                            int* __restrict__ bucket)
{
    int gid = blockIdx.x * 256 + threadIdx.x;
    if (gid >= EE) return;
    const int d = edge_dst[gid];
    const int p = atomicAdd(&cursor[d], 1);
    bucket[offsets[d] + p] = gid;
}

// one wave per node: sum its edge_attr rows (float2/lane, coalesced 512B/row)
__global__ __launch_bounds__(256) void gather_sum_kernel(
    const float* __restrict__ edge_attr,
    const int*   __restrict__ bucket,
    const int*   __restrict__ offsets,
    const int*   __restrict__ count,
    float*       __restrict__ agg)
{
    const int wid  = (blockIdx.x * 256 + threadIdx.x) >> 6;   // node id
    const int lane = threadIdx.x & 63;
    if (wid >= NN) return;
    const int start = offsets[wid];
    const int deg   = count[wid];
    float2 acc = make_float2(0.f, 0.f);
    for (int i = 0; i < deg; ++i) {
        const int e = bucket[start + i];
        const float2 v = reinterpret_cast<const float2*>(edge_attr)[e * 64 + lane];
        acc.x += v.x;
        acc.y += v.y;
    }
    reinterpret_cast<float2*>(agg)[wid * 64 + lane] = acc;
}

// ---------------------------------------------------------------------------
// K2: fused  concat -> LayerNorm -> external attention -> mix -> MLP -> out
//     One block = 16 nodes, 256 threads (4 waves). All f32 vector compute.
// ---------------------------------------------------------------------------
__global__ __launch_bounds__(256) void fused_node_kernel(
    const float* __restrict__ x,
    const float* __restrict__ agg,
    const float* __restrict__ u,
    const int*   __restrict__ batch,
    const float* __restrict__ Mk,
    const float* __restrict__ Mv,
    const float* __restrict__ gamma,
    const float* __restrict__ beta,
    const float* __restrict__ W1,
    const float* __restrict__ b1,
    const float* __restrict__ W2,
    const float* __restrict__ b2,
    float* __restrict__ out)
{
    __shared__ float s_ln[NT][LNS];   // normalized concat rows (later: mixed rows)
    __shared__ float s_wt[WTS];       // staged weight tiles (Mk/Mv/W1/W2)
    __shared__ float s_sc[NT][SCS];   // scores -> attention weights
    __shared__ float s_h[NT][HSS];    // MLP hidden

    const int tid   = threadIdx.x;
    const int node0 = blockIdx.x * NT;

    // ---- P0: gather concat + LayerNorm (one wave per node, 4 rounds) ----
    {
        const int lane = tid & 63;
        const int g    = tid >> 6;          // wave id 0..3
        for (int rep = 0; rep < 4; ++rep) {
            const int n  = g + rep * 4;     // node-in-block 0..15
            const int ng = node0 + n;
            const int bi = batch[ng];
            float v[5];
            #pragma unroll
            for (int j = 0; j < 5; ++j) {
                const int c = lane + 64 * j;        // uniform segment per j
                float val;
                if (c < 128)      val = x[ng * VIN + c];
                else if (c < 256) val = agg[ng * HIDN + (c - 128)];
                else              val = u[bi * UIN + (c - 256)];
                v[j] = val;
            }
            float s = 0.f, q = 0.f;
            #pragma unroll
            for (int j = 0; j < 5; ++j) { s += v[j]; q += v[j] * v[j]; }
            #pragma unroll
            for (int off = 32; off >= 1; off >>= 1) {
                s += __shfl_xor(s, off);
                q += __shfl_xor(q, off);
            }
            const float mu  = s * (1.0f / CATN);
            const float var = q * (1.0f / CATN) - mu * mu;
            const float rs  = rsqrtf(var + LN_EPS);
            #pragma unroll
            for (int j = 0; j < 5; ++j) {
                const int c = lane + 64 * j;
                s_ln[n][c] = (v[j] - mu) * rs * gamma[c] + beta[c];
            }
        }
    }
    __syncthreads();

    // ---- P1: scores[n][m] = ln[n] . Mk[m]   (K=320), m in 4 tiles of 32 ----
    {
        const int npair = tid & 7;          // 8 node-pairs
        const int mg    = tid >> 3;         // 0..31 local m
        const int n0 = npair * 2, n1 = n0 + 1;
        for (int mt = 0; mt < 4; ++mt) {
            for (int i = tid; i < 32 * CATN; i += 256) {
                const int r = i / CATN;
                const int c = i - r * CATN;
                s_wt[r * LNS + c] = Mk[(mt * 32 + r) * CATN + c];
            }
            __syncthreads();
            float acc0 = 0.f, acc1 = 0.f;
            const float* wrow = &s_wt[mg * LNS];
            #pragma unroll 4
            for (int c = 0; c < CATN; ++c) {
                const float w = wrow[c];
                acc0 += s_ln[n0][c] * w;
                acc1 += s_ln[n1][c] * w;
            }
            s_sc[n0][mt * 32 + mg] = acc0;
            s_sc[n1][mt * 32 + mg] = acc1;
            __syncthreads();
        }
    }

    // ---- P2: softmax over m (16 threads per node row) ----
    {
        const int r = tid >> 4;             // node 0..15
        const int j = tid & 15;
        float vals[8];
        float mx = -1e30f;
        #pragma unroll
        for (int k = 0; k < 8; ++k) {
            vals[k] = s_sc[r][j + 16 * k];
            mx = fmaxf(mx, vals[k]);
        }
        #pragma unroll
        for (int off = 8; off >= 1; off >>= 1) mx = fmaxf(mx, __shfl_xor(mx, off));
        float sum = 0.f;
        #pragma unroll
        for (int k = 0; k < 8; ++k) { vals[k] = __expf(vals[k] - mx); sum += vals[k]; }
        #pragma unroll
        for (int off = 8; off >= 1; off >>= 1) sum += __shfl_xor(sum, off);
        const float inv = 1.0f / sum;
        #pragma unroll
        for (int k = 0; k < 8; ++k) s_sc[r][j + 16 * k] = vals[k] * inv;
    }
    __syncthreads();

    // ---- P3: attn_out[n][c] = sum_m attn[n][m] * Mv[m][c]; mix into s_ln ----
    {
        const int n = tid >> 4;             // node 0..15
        const int j = tid & 15;             // c = j + 16k, k=0..19
        float acc[20];
        #pragma unroll
        for (int k = 0; k < 20; ++k) acc[k] = 0.f;
        for (int mt = 0; mt < 4; ++mt) {
            for (int i = tid; i < 32 * CATN; i += 256) {
                const int r = i / CATN;
                const int c = i - r * CATN;
                s_wt[r * LNS + c] = Mv[(mt * 32 + r) * CATN + c];
            }
            __syncthreads();
            #pragma unroll 4
            for (int m = 0; m < 32; ++m) {
                const float a = s_sc[n][mt * 32 + m];
                const float* wrow = &s_wt[m * LNS + j];
                #pragma unroll
                for (int k = 0; k < 20; ++k)
                    acc[k] += a * wrow[16 * k];
            }
            __syncthreads();
        }
        #pragma unroll
        for (int k = 0; k < 20; ++k) {
            const int c = j + 16 * k;
            s_ln[n][c] = 0.5f * acc[k] + 0.5f * s_ln[n][c];   // exclusive owner of (n,c)
        }
    }
    __syncthreads();

    // ---- P4: h = relu(mix @ W1 + b1)   (K=320 in 5 tiles of 64 rows) ----
    {
        const int npair = tid & 7;
        const int og    = tid >> 3;         // 0..31
        const int n0 = npair * 2, n1 = n0 + 1;
        const int o0 = og * 4;
        float acc[8];
        #pragma unroll
        for (int k = 0; k < 8; ++k) acc[k] = 0.f;
        for (int ct = 0; ct < 5; ++ct) {
            for (int i = tid; i < 64 * HIDN; i += 256) {
                const int r = i >> 7;
                const int o = i & 127;
                s_wt[r * HSS + o] = W1[(ct * 64 + r) * HIDN + o];
            }
            __syncthreads();
            #pragma unroll 4
            for (int cl = 0; cl < 64; ++cl) {
                const int c = ct * 64 + cl;
                const float a0 = s_ln[n0][c];
                const float a1 = s_ln[n1][c];
                const float4 w = *reinterpret_cast<const float4*>(&s_wt[cl * HSS + o0]);
                acc[0] += a0 * w.x; acc[1] += a0 * w.y; acc[2] += a0 * w.z; acc[3] += a0 * w.w;
                acc[4] += a1 * w.x; acc[5] += a1 * w.y; acc[6] += a1 * w.z; acc[7] += a1 * w.w;
            }
            __syncthreads();
        }
        float4 h0, h1;
        h0.x = fmaxf(acc[0] + b1[o0 + 0], 0.f);
        h0.y = fmaxf(acc[1] + b1[o0 + 1], 0.f);
        h0.z = fmaxf(acc[2] + b1[o0 + 2], 0.f);
        h0.w = fmaxf(acc[3] + b1[o0 + 3], 0.f);
        h1.x = fmaxf(acc[4] + b1[o0 + 0], 0.f);
        h1.y = fmaxf(acc[5] + b1[o0 + 1], 0.f);
        h1.z = fmaxf(acc[6] + b1[o0 + 2], 0.f);
        h1.w = fmaxf(acc[7] + b1[o0 + 3], 0.f);
        *reinterpret_cast<float4*>(&s_h[n0][o0]) = h0;
        *reinterpret_cast<float4*>(&s_h[n1][o0]) = h1;
    }
    __syncthreads();

    // ---- P5: y = h @ W2 + b2   (K=128 in 2 tiles of 64 rows) -> global ----
    {
        const int npair = tid & 7;
        const int og    = tid >> 3;
        const int n0 = npair * 2, n1 = n0 + 1;
        const int o0 = og * 4;
        float acc[8];
        #pragma unroll
        for (int k = 0; k < 8; ++k) acc[k] = 0.f;
        for (int ct = 0; ct < 2; ++ct) {
            for (int i = tid; i < 64 * HIDN; i += 256) {
                const int r = i >> 7;
                const int o = i & 127;
                s_wt[r * HSS + o] = W2[(ct * 64 + r) * HIDN + o];
            }
            __syncthreads();
            #pragma unroll 4
            for (int cl = 0; cl < 64; ++cl) {
                const int kk = ct * 64 + cl;
                const float a0 = s_h[n0][kk];
                const float a1 = s_h[n1][kk];
                const float4 w = *reinterpret_cast<const float4*>(&s_wt[cl * HSS + o0]);
                acc[0] += a0 * w.x; acc[1] += a0 * w.y; acc[2] += a0 * w.z; acc[3] += a0 * w.w;
                acc[4] += a1 * w.x; acc[5] += a1 * w.y; acc[6] += a1 * w.z; acc[7] += a1 * w.w;
            }
            __syncthreads();
        }
        float4 y0, y1;
        y0.x = acc[0] + b2[o0 + 0];
        y0.y = acc[1] + b2[o0 + 1];
        y0.z = acc[2] + b2[o0 + 2];
        y0.w = acc[3] + b2[o0 + 3];
        y1.x = acc[4] + b2[o0 + 0];
        y1.y = acc[5] + b2[o0 + 1];
        y1.z = acc[6] + b2[o0 + 2];
        y1.w = acc[7] + b2[o0 + 3];
        *reinterpret_cast<float4*>(&out[(node0 + n0) * HIDN + o0]) = y0;
        *reinterpret_cast<float4*>(&out[(node0 + n1) * HIDN + o0]) = y1;
    }
}

// ---------------------------------------------------------------------------
extern "C" void kernel_launch(void* const* d_in, const int* in_sizes, int n_in,
                              void* d_out, int out_size, void* d_ws, size_t ws_size,
                              hipStream_t stream)
{
    const float* x         = (const float*)d_in[0];
    const int*   edge_idx  = (const int*)  d_in[1];   // [2,E] int32
    const float* edge_attr = (const float*)d_in[2];
    const float* u         = (const float*)d_in[3];
    const int*   batch     = (const int*)  d_in[4];
    const float* Mk        = (const float*)d_in[5];
    const float* Mv        = (const float*)d_in[6];
    const float* gamma     = (const float*)d_in[7];
    const float* beta      = (const float*)d_in[8];
    const float* W1        = (const float*)d_in[9];
    const float* b1        = (const float*)d_in[10];
    const float* W2        = (const float*)d_in[11];
    const float* b2        = (const float*)d_in[12];
    float*       out       = (float*)d_out;

    // ws layout (floats/ints, all 4B):
    //   agg     : NN*HIDN f32   (25.6 MB)
    //   count   : NN int
    //   cursor  : NN int
    //   offsets : NN int
    //   partials: 256 int
    //   bucket  : EE int        (3.2 MB)
    char* w = (char*)d_ws;
    float* agg      = (float*)w;                 w += (size_t)NN * HIDN * sizeof(float);
    int*   count    = (int*)w;                   w += (size_t)NN * sizeof(int);
    int*   cursor   = (int*)w;                   w += (size_t)NN * sizeof(int);
    int*   offsets  = (int*)w;                   w += (size_t)NN * sizeof(int);
    int*   partials = (int*)w;                   w += 256 * sizeof(int);
    int*   bucket   = (int*)w;

    const int* edge_dst = edge_idx + EE;         // row 1 of edge_index

    // zero count + cursor (adjacent -> one memset)
    hipMemsetAsync(count, 0, (size_t)2 * NN * sizeof(int), stream);

    const int eb = (EE + 255) / 256;
    hist_kernel<<<eb, 256, 0, stream>>>(edge_dst, count);
    block_sum_kernel<<<SCAN_NB, 256, 0, stream>>>(count, partials);
    scan_partials_kernel<<<1, 256, 0, stream>>>(partials);
    make_offsets_kernel<<<SCAN_NB, 256, 0, stream>>>(count, partials, offsets);
    fill_kernel<<<eb, 256, 0, stream>>>(edge_dst, offsets, cursor, bucket);
    gather_sum_kernel<<<(NN * 64 + 255) / 256, 256, 0, stream>>>(edge_attr, bucket, offsets, count, agg);

    fused_node_kernel<<<NN / NT, 256, 0, stream>>>(x, agg, u, batch, Mk, Mv,
                                                   gamma, beta, W1, b1, W2, b2, out);
}

// Round 3
// 373.185 us; speedup vs baseline: 5.3269x; 2.2539x over previous
//
#include <hip/hip_runtime.h>

// Problem constants
#define NN   50000
#define EE   800000
#define VIN  128
#define HIDN 128
#define UIN  64
#define MEMN 128
#define CATN 320
#define LN_EPS 1e-5f
#define SCAN_NB 196

typedef __attribute__((ext_vector_type(8))) short short8;
typedef __attribute__((ext_vector_type(4))) float f32x4;
typedef __attribute__((ext_vector_type(4))) unsigned int uint4v;

__device__ inline unsigned short f32_bf16(float f) {
    unsigned u = __float_as_uint(f);
    return (unsigned short)((u + 0x7FFFu + ((u >> 16) & 1u)) >> 16);
}
// pack f32 -> (bf16_hi << 16) | bf16_lo   such that f ~= asfloat(p & 0xFFFF0000) + asfloat(p << 16)
__device__ inline unsigned pack_hl(float y) {
    unsigned u  = __float_as_uint(y);
    unsigned hi = (u + 0x7FFFu + ((u >> 16) & 1u)) & 0xFFFF0000u;
    float    lo = y - __uint_as_float(hi);
    unsigned v  = __float_as_uint(lo);
    unsigned l16 = ((v + 0x7FFFu + ((v >> 16) & 1u)) >> 16) & 0xFFFFu;
    return hi | l16;
}
__device__ inline void unpack_hl(const uint4v p0, const uint4v p1, short8& hi, short8& lo) {
    union { short8 s; unsigned u[4]; } H, L;
    H.u[0] = (p0.x >> 16) | (p0.y & 0xFFFF0000u);
    H.u[1] = (p0.z >> 16) | (p0.w & 0xFFFF0000u);
    H.u[2] = (p1.x >> 16) | (p1.y & 0xFFFF0000u);
    H.u[3] = (p1.z >> 16) | (p1.w & 0xFFFF0000u);
    L.u[0] = (p0.x & 0xFFFFu) | (p0.y << 16);
    L.u[1] = (p0.z & 0xFFFFu) | (p0.w << 16);
    L.u[2] = (p1.x & 0xFFFFu) | (p1.w << 16);  // fixed below
    L.u[2] = (p1.x & 0xFFFFu) | (p1.y << 16);
    L.u[3] = (p1.z & 0xFFFFu) | (p1.w << 16);
    hi = H.s; lo = L.s;
}

// ---------------------------------------------------------------------------
// CSR build: histogram -> scan -> bucket fill, then gather-sum (no f32 atomics)
// ---------------------------------------------------------------------------
__global__ void hist_kernel(const int* __restrict__ edge_dst, int* __restrict__ count)
{
    int gid = blockIdx.x * 256 + threadIdx.x;
    if (gid < EE) atomicAdd(&count[edge_dst[gid]], 1);
}

__global__ void block_sum_kernel(const int* __restrict__ count, int* __restrict__ partials)
{
    __shared__ int s[256];
    const int tid = threadIdx.x;
    const int gid = blockIdx.x * 256 + tid;
    s[tid] = (gid < NN) ? count[gid] : 0;
    __syncthreads();
    for (int off = 128; off >= 1; off >>= 1) {
        if (tid < off) s[tid] += s[tid + off];
        __syncthreads();
    }
    if (tid == 0) partials[blockIdx.x] = s[0];
}

__global__ void scan_partials_kernel(int* __restrict__ partials)
{
    __shared__ int s[256];
    const int tid = threadIdx.x;
    const int v = (tid < SCAN_NB) ? partials[tid] : 0;
    s[tid] = v;
    __syncthreads();
    for (int off = 1; off < 256; off <<= 1) {
        int t = (tid >= off) ? s[tid - off] : 0;
        __syncthreads();
        s[tid] += t;
        __syncthreads();
    }
    if (tid < SCAN_NB) partials[tid] = s[tid] - v;   // exclusive
}

__global__ void make_offsets_kernel(const int* __restrict__ count,
                                    const int* __restrict__ partials,
                                    int* __restrict__ offsets)
{
    __shared__ int s[256];
    const int tid = threadIdx.x;
    const int gid = blockIdx.x * 256 + tid;
    const int v = (gid < NN) ? count[gid] : 0;
    s[tid] = v;
    __syncthreads();
    for (int off = 1; off < 256; off <<= 1) {
        int t = (tid >= off) ? s[tid - off] : 0;
        __syncthreads();
        s[tid] += t;
        __syncthreads();
    }
    if (gid < NN) offsets[gid] = partials[blockIdx.x] + s[tid] - v;  // exclusive
}

__global__ void fill_kernel(const int* __restrict__ edge_dst,
                            const int* __restrict__ offsets,
                            int* __restrict__ cursor,
                            int* __restrict__ bucket)
{
    int gid = blockIdx.x * 256 + threadIdx.x;
    if (gid >= EE) return;
    const int d = edge_dst[gid];
    const int p = atomicAdd(&cursor[d], 1);
    bucket[offsets[d] + p] = gid;
}

__global__ __launch_bounds__(256) void gather_sum_kernel(
    const float* __restrict__ edge_attr,
    const int*   __restrict__ bucket,
    const int*   __restrict__ offsets,
    const int*   __restrict__ count,
    float*       __restrict__ agg)
{
    const int wid  = (blockIdx.x * 256 + threadIdx.x) >> 6;   // node id
    const int lane = threadIdx.x & 63;
    if (wid >= NN) return;
    const int start = offsets[wid];
    const int deg   = count[wid];
    float2 acc = make_float2(0.f, 0.f);
    for (int i = 0; i < deg; ++i) {
        const int e = bucket[start + i];
        const float2 v = reinterpret_cast<const float2*>(edge_attr)[e * 64 + lane];
        acc.x += v.x;
        acc.y += v.y;
    }
    reinterpret_cast<float2*>(agg)[wid * 64 + lane] = acc;
}

// ---------------------------------------------------------------------------
// Weight prep: split / transpose to MFMA-friendly layouts
// ---------------------------------------------------------------------------
__global__ void prep_mk_kernel(const float* __restrict__ Mk, unsigned* __restrict__ mk_pack)
{
    int i = blockIdx.x * 256 + threadIdx.x;
    if (i < MEMN * CATN) mk_pack[i] = pack_hl(Mk[i]);     // [m][k] native
}
__global__ void prep_mvt_kernel(const float* __restrict__ Mv, unsigned short* __restrict__ mv_t)
{
    int i = blockIdx.x * 256 + threadIdx.x;
    if (i < CATN * MEMN) {
        int c = i >> 7, m = i & 127;                      // mv_t[c][m] = Mv[m][c]
        mv_t[i] = f32_bf16(Mv[m * CATN + c]);
    }
}
__global__ void prep_w1t_kernel(const float* __restrict__ W1, unsigned short* __restrict__ w1_t)
{
    int i = blockIdx.x * 256 + threadIdx.x;
    if (i < HIDN * CATN) {
        int n = i / CATN, k = i - n * CATN;               // w1_t[n][k] = W1[k][n]
        w1_t[i] = f32_bf16(W1[k * HIDN + n]);
    }
}
__global__ void prep_w2t_kernel(const float* __restrict__ W2, unsigned short* __restrict__ w2_t)
{
    int i = blockIdx.x * 256 + threadIdx.x;
    if (i < HIDN * HIDN) {
        int n = i >> 7, k = i & 127;                      // w2_t[n][k] = W2[k][n]
        w2_t[i] = f32_bf16(W2[k * HIDN + n]);
    }
}

// ---------------------------------------------------------------------------
// LN kernel: concat -> LayerNorm -> packed hi|lo bf16 to global
// ---------------------------------------------------------------------------
__global__ __launch_bounds__(256) void ln_pack_kernel(
    const float* __restrict__ x,
    const float* __restrict__ agg,
    const float* __restrict__ u,
    const int*   __restrict__ batch,
    const float* __restrict__ gamma,
    const float* __restrict__ beta,
    unsigned*    __restrict__ ln_pack)
{
    const int tid  = threadIdx.x;
    const int lane = tid & 63;
    const int w    = tid >> 6;
    const int node0 = blockIdx.x * 16;
    for (int rep = 0; rep < 4; ++rep) {
        const int n  = w + rep * 4;
        const int ng = node0 + n;
        const int bi = batch[ng];
        float v[5];
        #pragma unroll
        for (int j = 0; j < 5; ++j) {
            const int c = lane + 64 * j;
            float val;
            if (c < 128)      val = x[ng * VIN + c];
            else if (c < 256) val = agg[ng * HIDN + (c - 128)];
            else              val = u[bi * UIN + (c - 256)];
            v[j] = val;
        }
        float s = 0.f, q = 0.f;
        #pragma unroll
        for (int j = 0; j < 5; ++j) { s += v[j]; q += v[j] * v[j]; }
        #pragma unroll
        for (int off = 32; off >= 1; off >>= 1) {
            s += __shfl_xor(s, off);
            q += __shfl_xor(q, off);
        }
        const float mu  = s * (1.0f / CATN);
        const float var = q * (1.0f / CATN) - mu * mu;
        const float rs  = rsqrtf(var + LN_EPS);
        #pragma unroll
        for (int j = 0; j < 5; ++j) {
            const int c = lane + 64 * j;
            const float y = (v[j] - mu) * rs * gamma[c] + beta[c];
            ln_pack[(size_t)ng * CATN + c] = pack_hl(y);
        }
    }
}

// ---------------------------------------------------------------------------
// Fused MFMA kernel: scores(3-split) -> softmax -> PV -> mix -> W1 -> W2
// 32 nodes/block, 256 threads (4 waves). 16x16x32 bf16 MFMA.
// ---------------------------------------------------------------------------
#define SSTR 132            // s_S f32 row stride
#define PSTR 136            // s_P bf16 row stride (17 x 16B -> conflict-free b128)
#define MSTR 328            // s_mix bf16 row stride (41 x 16B)
#define HSTR 136            // s_h bf16 row stride
#define LDSA (32 * MSTR * 2)            // 20992 B : union{ s_S f32[32][132], s_mix }
#define LDSB (32 * PSTR * 2)            // 8704 B  : union{ s_P, s_h }

__global__ __launch_bounds__(256) void node_mfma_kernel(
    const unsigned*       __restrict__ ln_pack,
    const unsigned*       __restrict__ mk_pack,
    const unsigned short* __restrict__ mv_t,
    const unsigned short* __restrict__ w1_t,
    const unsigned short* __restrict__ w2_t,
    const float*          __restrict__ b1,
    const float*          __restrict__ b2,
    float*                __restrict__ out)
{
    __shared__ __align__(16) char smem[LDSA + LDSB];
    float*          s_S   = (float*)smem;                         // [32][SSTR]
    unsigned short* s_mix = (unsigned short*)smem;                // [32][MSTR]
    unsigned short* s_P   = (unsigned short*)(smem + LDSA);       // [32][PSTR]
    unsigned short* s_h   = (unsigned short*)(smem + LDSA);       // [32][HSTR]

    const int tid  = threadIdx.x;
    const int wv   = tid >> 6;
    const int lane = tid & 63;
    const int l15  = lane & 15;
    const int l4   = lane >> 4;
    const int node0 = blockIdx.x * 32;

    const f32x4 zero4 = {0.f, 0.f, 0.f, 0.f};

    // ================= P1: S = ln @ Mk^T (hi/lo 3-way split) =================
    {
        f32x4 acc[2][2];
        #pragma unroll
        for (int mt = 0; mt < 2; ++mt)
            #pragma unroll
            for (int nt = 0; nt < 2; ++nt) acc[mt][nt] = zero4;

        int na[2];
        #pragma unroll
        for (int mt = 0; mt < 2; ++mt) {
            int n = node0 + mt * 16 + l15;
            na[mt] = (n < NN) ? n : (NN - 1);
        }
        int mrow[2];
        #pragma unroll
        for (int nt = 0; nt < 2; ++nt) mrow[nt] = (wv * 2 + nt) * 16 + l15;

        for (int kc = 0; kc < 10; ++kc) {
            const int koff = kc * 32 + l4 * 8;
            short8 ah[2], al[2], bh[2], bl[2];
            #pragma unroll
            for (int mt = 0; mt < 2; ++mt) {
                const uint4v* p = (const uint4v*)(ln_pack + (size_t)na[mt] * CATN + koff);
                unpack_hl(p[0], p[1], ah[mt], al[mt]);
            }
            #pragma unroll
            for (int nt = 0; nt < 2; ++nt) {
                const uint4v* p = (const uint4v*)(mk_pack + (size_t)mrow[nt] * CATN + koff);
                unpack_hl(p[0], p[1], bh[nt], bl[nt]);
            }
            #pragma unroll
            for (int mt = 0; mt < 2; ++mt)
                #pragma unroll
                for (int nt = 0; nt < 2; ++nt) {
                    acc[mt][nt] = __builtin_amdgcn_mfma_f32_16x16x32_bf16(ah[mt], bh[nt], acc[mt][nt], 0, 0, 0);
                    acc[mt][nt] = __builtin_amdgcn_mfma_f32_16x16x32_bf16(ah[mt], bl[nt], acc[mt][nt], 0, 0, 0);
                    acc[mt][nt] = __builtin_amdgcn_mfma_f32_16x16x32_bf16(al[mt], bh[nt], acc[mt][nt], 0, 0, 0);
                }
        }
        #pragma unroll
        for (int mt = 0; mt < 2; ++mt)
            #pragma unroll
            for (int nt = 0; nt < 2; ++nt)
                #pragma unroll
                for (int r = 0; r < 4; ++r)
                    s_S[(mt * 16 + l4 * 4 + r) * SSTR + (wv * 2 + nt) * 16 + l15] = acc[mt][nt][r];
    }
    __syncthreads();

    // ================= softmax over MEM=128 (8 threads/node) =================
    {
        const int nd = tid >> 3, j = tid & 7;
        const float* row = s_S + nd * SSTR + j * 16;
        float vals[16];
        float mx = -1e30f;
        #pragma unroll
        for (int i = 0; i < 16; ++i) { vals[i] = row[i]; mx = fmaxf(mx, vals[i]); }
        mx = fmaxf(mx, __shfl_xor(mx, 1));
        mx = fmaxf(mx, __shfl_xor(mx, 2));
        mx = fmaxf(mx, __shfl_xor(mx, 4));
        float sm = 0.f;
        #pragma unroll
        for (int i = 0; i < 16; ++i) { vals[i] = __expf(vals[i] - mx); sm += vals[i]; }
        sm += __shfl_xor(sm, 1);
        sm += __shfl_xor(sm, 2);
        sm += __shfl_xor(sm, 4);
        const float inv = 1.f / sm;
        unsigned* prow = (unsigned*)(s_P + nd * PSTR + j * 16);
        #pragma unroll
        for (int i2 = 0; i2 < 8; ++i2) {
            unsigned pk = (unsigned)f32_bf16(vals[2 * i2] * inv) |
                          ((unsigned)f32_bf16(vals[2 * i2 + 1] * inv) << 16);
            prow[i2] = pk;
        }
    }
    __syncthreads();

    // ================= PV: attn_out = P @ Mv  (N=320, single bf16) ===========
    {
        f32x4 acc[2][5];
        #pragma unroll
        for (int mt = 0; mt < 2; ++mt)
            #pragma unroll
            for (int nn = 0; nn < 5; ++nn) acc[mt][nn] = zero4;

        for (int kc = 0; kc < 4; ++kc) {
            const int koff = kc * 32 + l4 * 8;
            short8 ap[2];
            #pragma unroll
            for (int mt = 0; mt < 2; ++mt)
                ap[mt] = *(const short8*)(s_P + (mt * 16 + l15) * PSTR + koff);
            short8 bv[5];
            #pragma unroll
            for (int nn = 0; nn < 5; ++nn) {
                const int c = (wv * 5 + nn) * 16 + l15;
                bv[nn] = *(const short8*)(mv_t + (size_t)c * MEMN + koff);
            }
            #pragma unroll
            for (int mt = 0; mt < 2; ++mt)
                #pragma unroll
                for (int nn = 0; nn < 5; ++nn)
                    acc[mt][nn] = __builtin_amdgcn_mfma_f32_16x16x32_bf16(ap[mt], bv[nn], acc[mt][nn], 0, 0, 0);
        }
        // mix = 0.5*(attn + ln) -> s_mix (bf16)
        #pragma unroll
        for (int mt = 0; mt < 2; ++mt)
            #pragma unroll
            for (int nn = 0; nn < 5; ++nn)
                #pragma unroll
                for (int r = 0; r < 4; ++r) {
                    const int node_l = mt * 16 + l4 * 4 + r;
                    int ng = node0 + node_l; ng = (ng < NN) ? ng : (NN - 1);
                    const int c = (wv * 5 + nn) * 16 + l15;
                    const unsigned pk = ln_pack[(size_t)ng * CATN + c];
                    const float lnv = __uint_as_float(pk & 0xFFFF0000u) + __uint_as_float(pk << 16);
                    const float mixv = 0.5f * (acc[mt][nn][r] + lnv);
                    s_mix[node_l * MSTR + c] = f32_bf16(mixv);
                }
    }
    __syncthreads();

    // ================= W1: h = relu(mix @ W1 + b1) ===========================
    {
        f32x4 acc[2][2];
        #pragma unroll
        for (int mt = 0; mt < 2; ++mt)
            #pragma unroll
            for (int nt = 0; nt < 2; ++nt) acc[mt][nt] = zero4;

        for (int kc = 0; kc < 10; ++kc) {
            const int koff = kc * 32 + l4 * 8;
            short8 am[2], bw[2];
            #pragma unroll
            for (int mt = 0; mt < 2; ++mt)
                am[mt] = *(const short8*)(s_mix + (mt * 16 + l15) * MSTR + koff);
            #pragma unroll
            for (int nt = 0; nt < 2; ++nt) {
                const int n = (wv * 2 + nt) * 16 + l15;
                bw[nt] = *(const short8*)(w1_t + (size_t)n * CATN + koff);
            }
            #pragma unroll
            for (int mt = 0; mt < 2; ++mt)
                #pragma unroll
                for (int nt = 0; nt < 2; ++nt)
                    acc[mt][nt] = __builtin_amdgcn_mfma_f32_16x16x32_bf16(am[mt], bw[nt], acc[mt][nt], 0, 0, 0);
        }
        float bb[2];
        #pragma unroll
        for (int nt = 0; nt < 2; ++nt) bb[nt] = b1[(wv * 2 + nt) * 16 + l15];
        #pragma unroll
        for (int mt = 0; mt < 2; ++mt)
            #pragma unroll
            for (int nt = 0; nt < 2; ++nt)
                #pragma unroll
                for (int r = 0; r < 4; ++r) {
                    const int node_l = mt * 16 + l4 * 4 + r;
                    const int col = (wv * 2 + nt) * 16 + l15;
                    const float h = fmaxf(acc[mt][nt][r] + bb[nt], 0.f);
                    s_h[node_l * HSTR + col] = f32_bf16(h);
                }
    }
    __syncthreads();

    // ================= W2: y = h @ W2 + b2 -> out ============================
    {
        f32x4 acc[2][2];
        #pragma unroll
        for (int mt = 0; mt < 2; ++mt)
            #pragma unroll
            for (int nt = 0; nt < 2; ++nt) acc[mt][nt] = zero4;

        for (int kc = 0; kc < 4; ++kc) {
            const int koff = kc * 32 + l4 * 8;
            short8 ah[2], bw[2];
            #pragma unroll
            for (int mt = 0; mt < 2; ++mt)
                ah[mt] = *(const short8*)(s_h + (mt * 16 + l15) * HSTR + koff);
            #pragma unroll
            for (int nt = 0; nt < 2; ++nt) {
                const int n = (wv * 2 + nt) * 16 + l15;
                bw[nt] = *(const short8*)(w2_t + (size_t)n * HIDN + koff);
            }
            #pragma unroll
            for (int mt = 0; mt < 2; ++mt)
                #pragma unroll
                for (int nt = 0; nt < 2; ++nt)
                    acc[mt][nt] = __builtin_amdgcn_mfma_f32_16x16x32_bf16(ah[mt], bw[nt], acc[mt][nt], 0, 0, 0);
        }
        float bb[2];
        #pragma unroll
        for (int nt = 0; nt < 2; ++nt) bb[nt] = b2[(wv * 2 + nt) * 16 + l15];
        #pragma unroll
        for (int mt = 0; mt < 2; ++mt)
            #pragma unroll
            for (int nt = 0; nt < 2; ++nt)
                #pragma unroll
                for (int r = 0; r < 4; ++r) {
                    const int ng = node0 + mt * 16 + l4 * 4 + r;
                    if (ng < NN) {
                        const int col = (wv * 2 + nt) * 16 + l15;
                        out[(size_t)ng * HIDN + col] = acc[mt][nt][r] + bb[nt];
                    }
                }
    }
}

// ---------------------------------------------------------------------------
extern "C" void kernel_launch(void* const* d_in, const int* in_sizes, int n_in,
                              void* d_out, int out_size, void* d_ws, size_t ws_size,
                              hipStream_t stream)
{
    const float* x         = (const float*)d_in[0];
    const int*   edge_idx  = (const int*)  d_in[1];   // [2,E] int32
    const float* edge_attr = (const float*)d_in[2];
    const float* u         = (const float*)d_in[3];
    const int*   batch     = (const int*)  d_in[4];
    const float* Mk        = (const float*)d_in[5];
    const float* Mv        = (const float*)d_in[6];
    const float* gamma     = (const float*)d_in[7];
    const float* beta      = (const float*)d_in[8];
    const float* W1        = (const float*)d_in[9];
    const float* b1        = (const float*)d_in[10];
    const float* W2        = (const float*)d_in[11];
    const float* b2        = (const float*)d_in[12];
    float*       out       = (float*)d_out;

    // ws layout
    char* w = (char*)d_ws;
    float* agg       = (float*)w;      w += (size_t)NN * HIDN * sizeof(float);     // 25.6 MB
    int*   count     = (int*)w;        w += (size_t)NN * sizeof(int);
    int*   cursor    = (int*)w;        w += (size_t)NN * sizeof(int);
    int*   offsets   = (int*)w;        w += (size_t)NN * sizeof(int);
    int*   partials  = (int*)w;        w += 256 * sizeof(int);
    int*   bucket    = (int*)w;        w += (size_t)EE * sizeof(int);              // 3.2 MB
    w = (char*)(((size_t)w + 255) & ~(size_t)255);
    unsigned* ln_pk  = (unsigned*)w;   w += (size_t)NN * CATN * sizeof(unsigned);  // 64 MB
    unsigned* mk_pk  = (unsigned*)w;   w += (size_t)MEMN * CATN * sizeof(unsigned);
    unsigned short* mv_t = (unsigned short*)w; w += (size_t)CATN * MEMN * 2;
    unsigned short* w1_t = (unsigned short*)w; w += (size_t)HIDN * CATN * 2;
    unsigned short* w2_t = (unsigned short*)w; w += (size_t)HIDN * HIDN * 2;

    const int* edge_dst = edge_idx + EE;         // row 1 of edge_index

    hipMemsetAsync(count, 0, (size_t)2 * NN * sizeof(int), stream);

    const int eb = (EE + 255) / 256;
    hist_kernel<<<eb, 256, 0, stream>>>(edge_dst, count);
    block_sum_kernel<<<SCAN_NB, 256, 0, stream>>>(count, partials);
    scan_partials_kernel<<<1, 256, 0, stream>>>(partials);
    make_offsets_kernel<<<SCAN_NB, 256, 0, stream>>>(count, partials, offsets);
    fill_kernel<<<eb, 256, 0, stream>>>(edge_dst, offsets, cursor, bucket);
    gather_sum_kernel<<<(NN * 64 + 255) / 256, 256, 0, stream>>>(edge_attr, bucket, offsets, count, agg);

    prep_mk_kernel <<<(MEMN * CATN + 255) / 256, 256, 0, stream>>>(Mk, mk_pk);
    prep_mvt_kernel<<<(CATN * MEMN + 255) / 256, 256, 0, stream>>>(Mv, mv_t);
    prep_w1t_kernel<<<(HIDN * CATN + 255) / 256, 256, 0, stream>>>(W1, w1_t);
    prep_w2t_kernel<<<(HIDN * HIDN + 255) / 256, 256, 0, stream>>>(W2, w2_t);

    ln_pack_kernel<<<NN / 16, 256, 0, stream>>>(x, agg, u, batch, gamma, beta, ln_pk);

    node_mfma_kernel<<<(NN + 31) / 32, 256, 0, stream>>>(ln_pk, mk_pk, mv_t, w1_t, w2_t, b1, b2, out);
}

// Round 4
// 354.123 us; speedup vs baseline: 5.6136x; 1.0538x over previous
//
#include <hip/hip_runtime.h>

// Problem constants
#define NN   50000
#define EE   800000
#define VIN  128
#define HIDN 128
#define UIN  64
#define MEMN 128
#define CATN 320
#define LN_EPS 1e-5f
#define SCAN_NB 196

typedef __attribute__((ext_vector_type(8))) short short8;
typedef __attribute__((ext_vector_type(4))) float f32x4;
typedef __attribute__((ext_vector_type(4))) unsigned int uint4v;
typedef unsigned short ushort_t;

__device__ inline ushort_t f32_bf16(float f) {
    unsigned u = __float_as_uint(f);
    return (ushort_t)((u + 0x7FFFu + ((u >> 16) & 1u)) >> 16);
}
__device__ inline float bf16_f32(ushort_t h) {
    return __uint_as_float(((unsigned)h) << 16);
}
// pack f32 -> (bf16_hi << 16) | bf16_lo  with  f ~= hi + lo
__device__ inline unsigned pack_hl(float y) {
    unsigned u  = __float_as_uint(y);
    unsigned hi = (u + 0x7FFFu + ((u >> 16) & 1u)) & 0xFFFF0000u;
    float    lo = y - __uint_as_float(hi);
    unsigned v  = __float_as_uint(lo);
    unsigned l16 = ((v + 0x7FFFu + ((v >> 16) & 1u)) >> 16) & 0xFFFFu;
    return hi | l16;
}

// ---------------------------------------------------------------------------
// CSR build: histogram -> scan -> bucket fill
// ---------------------------------------------------------------------------
__global__ void hist_kernel(const int* __restrict__ edge_dst, int* __restrict__ count)
{
    int gid = blockIdx.x * 256 + threadIdx.x;
    if (gid < EE) atomicAdd(&count[edge_dst[gid]], 1);
}

__global__ void block_sum_kernel(const int* __restrict__ count, int* __restrict__ partials)
{
    __shared__ int s[256];
    const int tid = threadIdx.x;
    const int gid = blockIdx.x * 256 + tid;
    s[tid] = (gid < NN) ? count[gid] : 0;
    __syncthreads();
    for (int off = 128; off >= 1; off >>= 1) {
        if (tid < off) s[tid] += s[tid + off];
        __syncthreads();
    }
    if (tid == 0) partials[blockIdx.x] = s[0];
}

__global__ void scan_partials_kernel(int* __restrict__ partials)
{
    __shared__ int s[256];
    const int tid = threadIdx.x;
    const int v = (tid < SCAN_NB) ? partials[tid] : 0;
    s[tid] = v;
    __syncthreads();
    for (int off = 1; off < 256; off <<= 1) {
        int t = (tid >= off) ? s[tid - off] : 0;
        __syncthreads();
        s[tid] += t;
        __syncthreads();
    }
    if (tid < SCAN_NB) partials[tid] = s[tid] - v;   // exclusive
}

__global__ void make_offsets_kernel(const int* __restrict__ count,
                                    const int* __restrict__ partials,
                                    int* __restrict__ offsets)
{
    __shared__ int s[256];
    const int tid = threadIdx.x;
    const int gid = blockIdx.x * 256 + tid;
    const int v = (gid < NN) ? count[gid] : 0;
    s[tid] = v;
    __syncthreads();
    for (int off = 1; off < 256; off <<= 1) {
        int t = (tid >= off) ? s[tid - off] : 0;
        __syncthreads();
        s[tid] += t;
        __syncthreads();
    }
    if (gid < NN) offsets[gid] = partials[blockIdx.x] + s[tid] - v;  // exclusive
}

__global__ void fill_kernel(const int* __restrict__ edge_dst,
                            const int* __restrict__ offsets,
                            int* __restrict__ cursor,
                            int* __restrict__ bucket)
{
    int gid = blockIdx.x * 256 + threadIdx.x;
    if (gid >= EE) return;
    const int d = edge_dst[gid];
    const int p = atomicAdd(&cursor[d], 1);
    bucket[offsets[d] + p] = gid;
}

// ---------------------------------------------------------------------------
// gather + LayerNorm + hi|lo pack, fused: one wave per node
// ---------------------------------------------------------------------------
__global__ __launch_bounds__(256) void gather_ln_kernel(
    const float* __restrict__ edge_attr,
    const int*   __restrict__ bucket,
    const int*   __restrict__ offsets,
    const int*   __restrict__ count,
    const float* __restrict__ x,
    const float* __restrict__ u,
    const int*   __restrict__ batch,
    const float* __restrict__ gamma,
    const float* __restrict__ beta,
    unsigned*    __restrict__ ln_pk)
{
    const int wid  = (blockIdx.x * 256 + threadIdx.x) >> 6;   // node id
    const int lane = threadIdx.x & 63;
    if (wid >= NN) return;

    const int start = offsets[wid];
    const int deg   = count[wid];
    float2 a = make_float2(0.f, 0.f);
    for (int i = 0; i < deg; ++i) {
        const int e = bucket[start + i];
        const float2 v = reinterpret_cast<const float2*>(edge_attr)[e * 64 + lane];
        a.x += v.x;
        a.y += v.y;
    }
    const float2 xv = reinterpret_cast<const float2*>(x)[(size_t)wid * 64 + lane];
    const float  uv = u[batch[wid] * UIN + lane];

    float s = xv.x + xv.y + a.x + a.y + uv;
    float q = xv.x * xv.x + xv.y * xv.y + a.x * a.x + a.y * a.y + uv * uv;
    #pragma unroll
    for (int off = 32; off >= 1; off >>= 1) {
        s += __shfl_xor(s, off);
        q += __shfl_xor(q, off);
    }
    const float mu  = s * (1.0f / CATN);
    const float var = q * (1.0f / CATN) - mu * mu;
    const float rs  = rsqrtf(var + LN_EPS);

    const float2 g0 = reinterpret_cast<const float2*>(gamma)[lane];
    const float2 g1 = reinterpret_cast<const float2*>(gamma)[64 + lane];
    const float  g2 = gamma[256 + lane];
    const float2 t0 = reinterpret_cast<const float2*>(beta)[lane];
    const float2 t1 = reinterpret_cast<const float2*>(beta)[64 + lane];
    const float  t2 = beta[256 + lane];

    unsigned* row = ln_pk + (size_t)wid * CATN;
    uint2 p01, p23;
    p01.x = pack_hl((xv.x - mu) * rs * g0.x + t0.x);
    p01.y = pack_hl((xv.y - mu) * rs * g0.y + t0.y);
    p23.x = pack_hl((a.x - mu) * rs * g1.x + t1.x);
    p23.y = pack_hl((a.y - mu) * rs * g1.y + t1.y);
    reinterpret_cast<uint2*>(row)[lane]       = p01;      // cols 2l, 2l+1
    reinterpret_cast<uint2*>(row + 128)[lane] = p23;      // cols 128+2l, 129+2l
    row[256 + lane] = pack_hl((uv - mu) * rs * g2 + t2);  // col 256+l
}

// ---------------------------------------------------------------------------
// Weight prep
// ---------------------------------------------------------------------------
__global__ void prep_mk_kernel(const float* __restrict__ Mk,
                               ushort_t* __restrict__ mk_hi, ushort_t* __restrict__ mk_lo)
{
    int i = blockIdx.x * 256 + threadIdx.x;
    if (i < MEMN * CATN) {
        const float f = Mk[i];
        const ushort_t h = f32_bf16(f);
        mk_hi[i] = h;
        mk_lo[i] = f32_bf16(f - bf16_f32(h));
    }
}
__global__ void prep_mvt_kernel(const float* __restrict__ Mv, ushort_t* __restrict__ mv_t)
{
    int i = blockIdx.x * 256 + threadIdx.x;
    if (i < CATN * MEMN) {
        int c = i >> 7, m = i & 127;                      // mv_t[c][m] = Mv[m][c]
        mv_t[i] = f32_bf16(Mv[m * CATN + c]);
    }
}
__global__ void prep_w1t_kernel(const float* __restrict__ W1, ushort_t* __restrict__ w1_t)
{
    int i = blockIdx.x * 256 + threadIdx.x;
    if (i < HIDN * CATN) {
        int n = i / CATN, k = i - n * CATN;               // w1_t[n][k] = W1[k][n]
        w1_t[i] = f32_bf16(W1[k * HIDN + n]);
    }
}
__global__ void prep_w2t_kernel(const float* __restrict__ W2, ushort_t* __restrict__ w2_t)
{
    int i = blockIdx.x * 256 + threadIdx.x;
    if (i < HIDN * HIDN) {
        int n = i >> 7, k = i & 127;                      // w2_t[n][k] = W2[k][n]
        w2_t[i] = f32_bf16(W2[k * HIDN + n]);
    }
}

// ---------------------------------------------------------------------------
// Fused MFMA kernel: scores(3-split) -> softmax -> PV -> mix(in-place) -> MLP
// 32 nodes/block, 256 threads (4 waves). 16x16x32 bf16 MFMA.
// LDS planes: hi/lo bf16 ln rows staged once; no unpack inside MFMA loops.
// ---------------------------------------------------------------------------
#define MSTR 328            // bf16 row stride: 656B = 41 x 16B (odd -> 2-way max)
#define SSTR 132            // f32 row stride : 528B = 33 x 16B
#define PSTR 136            // bf16 row stride: 272B = 17 x 16B

__global__ __launch_bounds__(256) void node_mfma_kernel(
    const unsigned* __restrict__ ln_pk,
    const ushort_t* __restrict__ mk_hi,
    const ushort_t* __restrict__ mk_lo,
    const ushort_t* __restrict__ mv_t,
    const ushort_t* __restrict__ w1_t,
    const ushort_t* __restrict__ w2_t,
    const float*    __restrict__ b1,
    const float*    __restrict__ b2,
    float*          __restrict__ out)
{
    __shared__ __align__(16) ushort_t s_lnh[32 * MSTR];   // ln hi -> later mix
    __shared__ __align__(16) ushort_t s_lnl[32 * MSTR];   // ln lo
    __shared__ __align__(16) float    s_S[32 * SSTR];     // scores
    __shared__ __align__(16) ushort_t s_P[32 * PSTR];     // attn bf16 -> later h

    const int tid  = threadIdx.x;
    const int wv   = tid >> 6;
    const int lane = tid & 63;
    const int l15  = lane & 15;
    const int l4   = lane >> 4;
    const int node0 = blockIdx.x * 32;

    const f32x4 zero4 = {0.f, 0.f, 0.f, 0.f};

    // ---- stage: ln_pk (32 rows) -> s_lnh / s_lnl, split once ----
    for (int j = tid; j < 32 * 80; j += 256) {
        const int nl = j / 80;
        const int c0 = (j - nl * 80) * 4;
        int ng = node0 + nl; ng = (ng < NN) ? ng : (NN - 1);
        const uint4v p = *(const uint4v*)(ln_pk + (size_t)ng * CATN + c0);
        ushort_t* ph = s_lnh + nl * MSTR + c0;
        ushort_t* pl = s_lnl + nl * MSTR + c0;
        ph[0] = (ushort_t)(p.x >> 16);  pl[0] = (ushort_t)(p.x & 0xFFFFu);
        ph[1] = (ushort_t)(p.y >> 16);  pl[1] = (ushort_t)(p.y & 0xFFFFu);
        ph[2] = (ushort_t)(p.z >> 16);  pl[2] = (ushort_t)(p.z & 0xFFFFu);
        ph[3] = (ushort_t)(p.w >> 16);  pl[3] = (ushort_t)(p.w & 0xFFFFu);
    }
    __syncthreads();

    // ================= P1: S = ln @ Mk^T (hi/lo 3-way split) =================
    {
        f32x4 acc[2][2];
        #pragma unroll
        for (int mt = 0; mt < 2; ++mt)
            #pragma unroll
            for (int nt = 0; nt < 2; ++nt) acc[mt][nt] = zero4;

        for (int kc = 0; kc < 10; ++kc) {
            const int koff = kc * 32 + l4 * 8;
            short8 ah[2], al[2], bh[2], bl[2];
            #pragma unroll
            for (int mt = 0; mt < 2; ++mt) {
                ah[mt] = *(const short8*)(s_lnh + (mt * 16 + l15) * MSTR + koff);
                al[mt] = *(const short8*)(s_lnl + (mt * 16 + l15) * MSTR + koff);
            }
            #pragma unroll
            for (int nt = 0; nt < 2; ++nt) {
                const int mr = (wv * 2 + nt) * 16 + l15;
                bh[nt] = *(const short8*)(mk_hi + (size_t)mr * CATN + koff);
                bl[nt] = *(const short8*)(mk_lo + (size_t)mr * CATN + koff);
            }
            #pragma unroll
            for (int mt = 0; mt < 2; ++mt)
                #pragma unroll
                for (int nt = 0; nt < 2; ++nt) {
                    acc[mt][nt] = __builtin_amdgcn_mfma_f32_16x16x32_bf16(ah[mt], bh[nt], acc[mt][nt], 0, 0, 0);
                    acc[mt][nt] = __builtin_amdgcn_mfma_f32_16x16x32_bf16(ah[mt], bl[nt], acc[mt][nt], 0, 0, 0);
                    acc[mt][nt] = __builtin_amdgcn_mfma_f32_16x16x32_bf16(al[mt], bh[nt], acc[mt][nt], 0, 0, 0);
                }
        }
        #pragma unroll
        for (int mt = 0; mt < 2; ++mt)
            #pragma unroll
            for (int nt = 0; nt < 2; ++nt)
                #pragma unroll
                for (int r = 0; r < 4; ++r)
                    s_S[(mt * 16 + l4 * 4 + r) * SSTR + (wv * 2 + nt) * 16 + l15] = acc[mt][nt][r];
    }
    __syncthreads();

    // ================= softmax over MEM=128 (8 threads/node) =================
    {
        const int nd = tid >> 3, j = tid & 7;
        const float* row = s_S + nd * SSTR + j * 16;
        float vals[16];
        float mx = -1e30f;
        #pragma unroll
        for (int i = 0; i < 16; ++i) { vals[i] = row[i]; mx = fmaxf(mx, vals[i]); }
        mx = fmaxf(mx, __shfl_xor(mx, 1));
        mx = fmaxf(mx, __shfl_xor(mx, 2));
        mx = fmaxf(mx, __shfl_xor(mx, 4));
        float sm = 0.f;
        #pragma unroll
        for (int i = 0; i < 16; ++i) { vals[i] = __expf(vals[i] - mx); sm += vals[i]; }
        sm += __shfl_xor(sm, 1);
        sm += __shfl_xor(sm, 2);
        sm += __shfl_xor(sm, 4);
        const float inv = 1.f / sm;
        unsigned* prow = (unsigned*)(s_P + nd * PSTR + j * 16);
        #pragma unroll
        for (int i2 = 0; i2 < 8; ++i2) {
            unsigned pk = (unsigned)f32_bf16(vals[2 * i2] * inv) |
                          ((unsigned)f32_bf16(vals[2 * i2 + 1] * inv) << 16);
            prow[i2] = pk;
        }
    }
    __syncthreads();

    // ====== PV: attn = P @ Mv (N=320); mix = 0.5*(attn+ln) -> s_lnh in-place ==
    {
        f32x4 acc[2][5];
        #pragma unroll
        for (int mt = 0; mt < 2; ++mt)
            #pragma unroll
            for (int nn = 0; nn < 5; ++nn) acc[mt][nn] = zero4;

        for (int kc = 0; kc < 4; ++kc) {
            const int koff = kc * 32 + l4 * 8;
            short8 ap[2];
            #pragma unroll
            for (int mt = 0; mt < 2; ++mt)
                ap[mt] = *(const short8*)(s_P + (mt * 16 + l15) * PSTR + koff);
            short8 bv[5];
            #pragma unroll
            for (int nn = 0; nn < 5; ++nn) {
                const int c = (wv * 5 + nn) * 16 + l15;
                bv[nn] = *(const short8*)(mv_t + (size_t)c * MEMN + koff);
            }
            #pragma unroll
            for (int mt = 0; mt < 2; ++mt)
                #pragma unroll
                for (int nn = 0; nn < 5; ++nn)
                    acc[mt][nn] = __builtin_amdgcn_mfma_f32_16x16x32_bf16(ap[mt], bv[nn], acc[mt][nn], 0, 0, 0);
        }
        // mix: each (node,c) element has a unique owner lane -> in-place safe
        #pragma unroll
        for (int mt = 0; mt < 2; ++mt)
            #pragma unroll
            for (int nn = 0; nn < 5; ++nn)
                #pragma unroll
                for (int r = 0; r < 4; ++r) {
                    const int node_l = mt * 16 + l4 * 4 + r;
                    const int c = (wv * 5 + nn) * 16 + l15;
                    const int idx = node_l * MSTR + c;
                    const float lnv = bf16_f32(s_lnh[idx]) + bf16_f32(s_lnl[idx]);
                    s_lnh[idx] = f32_bf16(0.5f * (acc[mt][nn][r] + lnv));
                }
    }
    __syncthreads();

    // ================= W1: h = relu(mix @ W1 + b1) -> s_P region ============
    {
        f32x4 acc[2][2];
        #pragma unroll
        for (int mt = 0; mt < 2; ++mt)
            #pragma unroll
            for (int nt = 0; nt < 2; ++nt) acc[mt][nt] = zero4;

        for (int kc = 0; kc < 10; ++kc) {
            const int koff = kc * 32 + l4 * 8;
            short8 am[2], bw[2];
            #pragma unroll
            for (int mt = 0; mt < 2; ++mt)
                am[mt] = *(const short8*)(s_lnh + (mt * 16 + l15) * MSTR + koff);
            #pragma unroll
            for (int nt = 0; nt < 2; ++nt) {
                const int n = (wv * 2 + nt) * 16 + l15;
                bw[nt] = *(const short8*)(w1_t + (size_t)n * CATN + koff);
            }
            #pragma unroll
            for (int mt = 0; mt < 2; ++mt)
                #pragma unroll
                for (int nt = 0; nt < 2; ++nt)
                    acc[mt][nt] = __builtin_amdgcn_mfma_f32_16x16x32_bf16(am[mt], bw[nt], acc[mt][nt], 0, 0, 0);
        }
        float bb[2];
        #pragma unroll
        for (int nt = 0; nt < 2; ++nt) bb[nt] = b1[(wv * 2 + nt) * 16 + l15];
        __syncthreads();   // all W1 A-reads done before s_P region is reused as h
        #pragma unroll
        for (int mt = 0; mt < 2; ++mt)
            #pragma unroll
            for (int nt = 0; nt < 2; ++nt)
                #pragma unroll
                for (int r = 0; r < 4; ++r) {
                    const int node_l = mt * 16 + l4 * 4 + r;
                    const int col = (wv * 2 + nt) * 16 + l15;
                    s_P[node_l * PSTR + col] = f32_bf16(fmaxf(acc[mt][nt][r] + bb[nt], 0.f));
                }
    }
    __syncthreads();

    // ================= W2: y = h @ W2 + b2 -> out ============================
    {
        f32x4 acc[2][2];
        #pragma unroll
        for (int mt = 0; mt < 2; ++mt)
            #pragma unroll
            for (int nt = 0; nt < 2; ++nt) acc[mt][nt] = zero4;

        for (int kc = 0; kc < 4; ++kc) {
            const int koff = kc * 32 + l4 * 8;
            short8 ah[2], bw[2];
            #pragma unroll
            for (int mt = 0; mt < 2; ++mt)
                ah[mt] = *(const short8*)(s_P + (mt * 16 + l15) * PSTR + koff);
            #pragma unroll
            for (int nt = 0; nt < 2; ++nt) {
                const int n = (wv * 2 + nt) * 16 + l15;
                bw[nt] = *(const short8*)(w2_t + (size_t)n * HIDN + koff);
            }
            #pragma unroll
            for (int mt = 0; mt < 2; ++mt)
                #pragma unroll
                for (int nt = 0; nt < 2; ++nt)
                    acc[mt][nt] = __builtin_amdgcn_mfma_f32_16x16x32_bf16(ah[mt], bw[nt], acc[mt][nt], 0, 0, 0);
        }
        float bb[2];
        #pragma unroll
        for (int nt = 0; nt < 2; ++nt) bb[nt] = b2[(wv * 2 + nt) * 16 + l15];
        #pragma unroll
        for (int mt = 0; mt < 2; ++mt)
            #pragma unroll
            for (int nt = 0; nt < 2; ++nt)
                #pragma unroll
                for (int r = 0; r < 4; ++r) {
                    const int ng = node0 + mt * 16 + l4 * 4 + r;
                    if (ng < NN) {
                        const int col = (wv * 2 + nt) * 16 + l15;
                        out[(size_t)ng * HIDN + col] = acc[mt][nt][r] + bb[nt];
                    }
                }
    }
}

// ---------------------------------------------------------------------------
extern "C" void kernel_launch(void* const* d_in, const int* in_sizes, int n_in,
                              void* d_out, int out_size, void* d_ws, size_t ws_size,
                              hipStream_t stream)
{
    const float* x         = (const float*)d_in[0];
    const int*   edge_idx  = (const int*)  d_in[1];   // [2,E] int32
    const float* edge_attr = (const float*)d_in[2];
    const float* u         = (const float*)d_in[3];
    const int*   batch     = (const int*)  d_in[4];
    const float* Mk        = (const float*)d_in[5];
    const float* Mv        = (const float*)d_in[6];
    const float* gamma     = (const float*)d_in[7];
    const float* beta      = (const float*)d_in[8];
    const float* W1        = (const float*)d_in[9];
    const float* b1        = (const float*)d_in[10];
    const float* W2        = (const float*)d_in[11];
    const float* b2        = (const float*)d_in[12];
    float*       out       = (float*)d_out;

    // ws layout
    char* w = (char*)d_ws;
    int*   count     = (int*)w;        w += (size_t)NN * sizeof(int);
    int*   cursor    = (int*)w;        w += (size_t)NN * sizeof(int);
    int*   offsets   = (int*)w;        w += (size_t)NN * sizeof(int);
    int*   partials  = (int*)w;        w += 256 * sizeof(int);
    int*   bucket    = (int*)w;        w += (size_t)EE * sizeof(int);              // 3.2 MB
    w = (char*)(((size_t)w + 255) & ~(size_t)255);
    unsigned* ln_pk  = (unsigned*)w;   w += (size_t)NN * CATN * sizeof(unsigned);  // 64 MB
    ushort_t* mk_hi  = (ushort_t*)w;   w += (size_t)MEMN * CATN * 2;
    ushort_t* mk_lo  = (ushort_t*)w;   w += (size_t)MEMN * CATN * 2;
    ushort_t* mv_t   = (ushort_t*)w;   w += (size_t)CATN * MEMN * 2;
    ushort_t* w1_t   = (ushort_t*)w;   w += (size_t)HIDN * CATN * 2;
    ushort_t* w2_t   = (ushort_t*)w;   w += (size_t)HIDN * HIDN * 2;

    const int* edge_dst = edge_idx + EE;         // row 1 of edge_index

    hipMemsetAsync(count, 0, (size_t)2 * NN * sizeof(int), stream);

    const int eb = (EE + 255) / 256;
    hist_kernel<<<eb, 256, 0, stream>>>(edge_dst, count);
    block_sum_kernel<<<SCAN_NB, 256, 0, stream>>>(count, partials);
    scan_partials_kernel<<<1, 256, 0, stream>>>(partials);
    make_offsets_kernel<<<SCAN_NB, 256, 0, stream>>>(count, partials, offsets);
    fill_kernel<<<eb, 256, 0, stream>>>(edge_dst, offsets, cursor, bucket);

    prep_mk_kernel <<<(MEMN * CATN + 255) / 256, 256, 0, stream>>>(Mk, mk_hi, mk_lo);
    prep_mvt_kernel<<<(CATN * MEMN + 255) / 256, 256, 0, stream>>>(Mv, mv_t);
    prep_w1t_kernel<<<(HIDN * CATN + 255) / 256, 256, 0, stream>>>(W1, w1_t);
    prep_w2t_kernel<<<(HIDN * HIDN + 255) / 256, 256, 0, stream>>>(W2, w2_t);

    gather_ln_kernel<<<(NN * 64 + 255) / 256, 256, 0, stream>>>(
        edge_attr, bucket, offsets, count, x, u, batch, gamma, beta, ln_pk);

    node_mfma_kernel<<<(NN + 31) / 32, 256, 0, stream>>>(
        ln_pk, mk_hi, mk_lo, mv_t, w1_t, w2_t, b1, b2, out);
}